// Round 22
// baseline (70.041 us; speedup 1.0000x reference)
//
#include <hip/hip_runtime.h>
#include <stdint.h>

#define DM 256
#define NHEADS 8
#define DH 32
#define SEQ 2048
#define NB 4
#define MTOT (NB*SEQ)

// scale * log2(e) : scores computed in exp2 domain
#define QSCALE 0.2550351270433207f

typedef __attribute__((ext_vector_type(8))) __bf16 bf16x8;
typedef __attribute__((ext_vector_type(4))) short s16x4;
typedef __attribute__((ext_vector_type(8))) short s16x8;
typedef __attribute__((ext_vector_type(4))) unsigned int u32x4;
typedef __attribute__((ext_vector_type(4))) float f32x4;
typedef __attribute__((ext_vector_type(16))) float f32x16;

__device__ inline short f2bf(float f){
  uint32_t u = __builtin_bit_cast(uint32_t, f);
  u += 0x7fffu + ((u >> 16) & 1u);
  return (short)(u >> 16);
}

// fragment-packed offset for ([16-row tile] t, kc, lg, lr): one contiguous
// 1KB block per wave fragment-load.
#define WFRAG(t_, kc_, lg_, lr_) (((((size_t)(t_)*8 + (kc_))*4 + (lg_))*16 + (lr_))*8)

// ---------------------------------------------------------------------------
// prep: fp32 weights -> bf16 (Wq scaled by QSCALE), fragment-packed (r20
// win: -18.5us).
// ---------------------------------------------------------------------------
__global__ __launch_bounds__(256) void prep(
    const float* __restrict__ Wq, const float* __restrict__ Wk,
    const float* __restrict__ Wv, const float* __restrict__ Wo,
    short* __restrict__ Wqb, short* __restrict__ Wkb,
    short* __restrict__ Wvb, short* __restrict__ Wob)
{
  const int i = (blockIdx.x*256 + threadIdx.x)*8;
  const int seg = i >> 16;
  const int off = i & 65535;
  const float* src = seg==0?Wq: seg==1?Wk: seg==2?Wv:Wo;
  short* dst       = seg==0?Wqb: seg==1?Wkb: seg==2?Wvb:Wob;
  const float sc = (seg==0) ? QSCALE : 1.0f;
  float4 a = *(const float4*)(src + off);
  float4 b = *(const float4*)(src + off + 4);
  s16x8 o;
  o[0]=f2bf(a.x*sc); o[1]=f2bf(a.y*sc); o[2]=f2bf(a.z*sc); o[3]=f2bf(a.w*sc);
  o[4]=f2bf(b.x*sc); o[5]=f2bf(b.y*sc); o[6]=f2bf(b.z*sc); o[7]=f2bf(b.w*sc);
  const int row = off >> 8, col = off & 255;
  *(s16x8*)(dst + WFRAG(row>>4, col>>5, (col>>3)&3, row&15)) = o;
}

// ---------------------------------------------------------------------------
// xprep: fp32 X (query/key/value) -> bf16 fragment-packed. Removes qkv's
// 16-line A-fragment gather (same principle as W-packing) and its inline
// cvts. Identical f2bf rounding -> bit-identical results.
// ---------------------------------------------------------------------------
__global__ __launch_bounds__(256) void xprep(
    const float* __restrict__ Xq, const float* __restrict__ Xk,
    const float* __restrict__ Xv,
    short* __restrict__ Xqp, short* __restrict__ Xkp, short* __restrict__ Xvp)
{
  const int i = (blockIdx.x*256 + threadIdx.x)*8;   // elem index in one array
  const int seg = blockIdx.y;
  const float* src = seg==0?Xq: seg==1?Xk:Xv;
  short* dst       = seg==0?Xqp: seg==1?Xkp:Xvp;
  float4 a = *(const float4*)(src + i);
  float4 b = *(const float4*)(src + i + 4);
  s16x8 o;
  o[0]=f2bf(a.x); o[1]=f2bf(a.y); o[2]=f2bf(a.z); o[3]=f2bf(a.w);
  o[4]=f2bf(b.x); o[5]=f2bf(b.y); o[6]=f2bf(b.z); o[7]=f2bf(b.w);
  const int row = i >> 8, col = i & 255;
  *(s16x8*)(dst + WFRAG(row>>4, col>>5, (col>>3)&3, row&15)) = o;
}

// ---------------------------------------------------------------------------
// QKV projection (r15 shape): packed bf16 W AND packed bf16 X (A-loads now
// contiguous 1KB wave-blocks, no inline cvt). n-split=2, 2 waves x 16 rows.
// mode 0/1 (Q,K): SWAPPED mfma(W,X) -> s16x4 stores.
// mode 2 (V): original order, TILED [b,h][kv_tile][d=32][kv_in=32] layout.
// ---------------------------------------------------------------------------
__global__ __launch_bounds__(128) void qkv_proj(
    const short* __restrict__ Xqp, const short* __restrict__ Xkp, const short* __restrict__ Xvp,
    const short* __restrict__ Wqb, const short* __restrict__ Wkb, const short* __restrict__ Wvb,
    const float* __restrict__ bq, const float* __restrict__ bk, const float* __restrict__ bv,
    short* __restrict__ Qh, short* __restrict__ Kh, short* __restrict__ Vt)
{
  const int mode = blockIdx.z;
  const short* Xp   = mode==0 ? Xqp : (mode==1 ? Xkp : Xvp);
  const short* Wb   = mode==0 ? Wqb : (mode==1 ? Wkb : Wvb);
  const float* bias = mode==0 ? bq : (mode==1 ? bk : bv);
  short* dst        = mode==0 ? Qh : (mode==1 ? Kh : Vt);
  const float bscale = (mode==0) ? QSCALE : 1.0f;

  const int wid = threadIdx.x >> 6, lane = threadIdx.x & 63;
  const int lr = lane & 15, lg = lane >> 4;
  const int m0 = blockIdx.x*32 + wid*16;
  const int nf0 = blockIdx.y*8;

  f32x4 acc[8] = {};
  const int bb = m0 >> 11;
  const int mt = m0 >> 4;

  if (mode < 2) {
    // ---- swapped: D[outcol][m], lane: m = m0+lr, cols = nf*16 + lg*4 + r
    #pragma unroll
    for (int kc = 0; kc < 8; ++kc) {
      bf16x8 a = *(const bf16x8*)(Xp + WFRAG(mt, kc, lg, lr));
      #pragma unroll
      for (int nfi=0; nfi<8; ++nfi) {
        bf16x8 b = *(const bf16x8*)(Wb + WFRAG(nf0+nfi, kc, lg, lr));
        acc[nfi] = __builtin_amdgcn_mfma_f32_16x16x32_bf16(b, a, acc[nfi], 0,0,0);
      }
    }
    const int m = m0 + lr;
    const int l = m & (SEQ-1);
    #pragma unroll
    for (int nfi=0; nfi<8; ++nfi) {
      const int colbase = (nf0+nfi)*16;
      const int h = colbase >> 5;
      const int dbase = (colbase & 31) + lg*4;
      float4 b4 = *(const float4*)(bias + colbase + lg*4);
      s16x4 pk;
      pk[0] = f2bf(acc[nfi][0] + b4.x*bscale);
      pk[1] = f2bf(acc[nfi][1] + b4.y*bscale);
      pk[2] = f2bf(acc[nfi][2] + b4.z*bscale);
      pk[3] = f2bf(acc[nfi][3] + b4.w*bscale);
      *(s16x4*)(dst + ((size_t)(bb*NHEADS + h)*SEQ + l)*DH + dbase) = pk;
    }
  } else {
    // ---- original: D[m][outcol], lane: col = nf*16+lr, rows = li0 + r
    #pragma unroll
    for (int kc = 0; kc < 8; ++kc) {
      bf16x8 a = *(const bf16x8*)(Xp + WFRAG(mt, kc, lg, lr));
      #pragma unroll
      for (int nfi=0; nfi<8; ++nfi) {
        bf16x8 b = *(const bf16x8*)(Wb + WFRAG(nf0+nfi, kc, lg, lr));
        acc[nfi] = __builtin_amdgcn_mfma_f32_16x16x32_bf16(a, b, acc[nfi], 0,0,0);
      }
    }
    const int li0 = (m0 & (SEQ-1)) + lg*4;
    #pragma unroll
    for (int nfi=0; nfi<8; ++nfi) {
      const int col = (nf0+nfi)*16 + lr;
      const float bv_ = bias[col];
      const int h = col >> 5, d = col & 31;
      s16x4 pk;
      #pragma unroll
      for (int r=0;r<4;r++) pk[r] = f2bf(acc[nfi][r] + bv_);
      *(s16x4*)(dst + (((size_t)(bb*NHEADS + h)*(SEQ/32) + (li0>>5))*DH + d)*32 + (li0&31)) = pk;
    }
  }
}

// ---------------------------------------------------------------------------
// Flash attention (r21 loop, unchanged): 32x32x16 MFMA, swapped-QK, no max
// tracking, no kv-split (4 adjacent q-tiles share kv via L1), no LDS/
// barriers, dual accumulator chains, distance-1 prefetch, setprio.
// NEW: ctx written in FRAGMENT-PACKED layout (kc=head, lg=rg): store becomes
// 256B-contiguous per lane-quarter and out_ln's A-load becomes contiguous.
// ---------------------------------------------------------------------------
#if __has_builtin(__builtin_amdgcn_permlane32_swap)
typedef unsigned int u32x2v __attribute__((ext_vector_type(2)));
#define PSWAP(a_, b_) do { u32x2v r_ = __builtin_amdgcn_permlane32_swap((a_), (b_), false, false); (a_) = r_[0]; (b_) = r_[1]; } while(0)
#else
#define PSWAP(a_, b_) asm("s_nop 1\n\tv_permlane32_swap_b32 %0, %1" : "+v"(a_), "+v"(b_))
#endif

#define LOADKV(K0_,K1_,V0_,V1_, kvb_) do { \
  const short* kp_ = Kb + (size_t)((kvb_) + l31)*DH + hi8; \
  K0_ = *(const bf16x8*)kp_; K1_ = *(const bf16x8*)(kp_ + 16); \
  const short* vp_ = Vb + ((size_t)(((kvb_) >> 5)*32) + l31)*32 + hi8; \
  V0_ = *(const bf16x8*)vp_; V1_ = *(const bf16x8*)(vp_ + 16); \
} while(0)

#define ATTN_TILE(O_, l_, K0_, K1_, V0_, V1_) do { \
  __builtin_amdgcn_s_setprio(1); \
  f32x16 S_ = __builtin_amdgcn_mfma_f32_32x32x16_bf16(K0_, Q0, zf16, 0,0,0); \
  S_ = __builtin_amdgcn_mfma_f32_32x32x16_bf16(K1_, Q1, S_, 0,0,0); \
  __builtin_amdgcn_s_setprio(0); \
  float p_[16]; \
  _Pragma("unroll") for (int r_=0;r_<16;r_++) p_[r_] = __builtin_amdgcn_exp2f(S_[r_]); \
  l_ += (((p_[0]+p_[1])+(p_[2]+p_[3]))+((p_[4]+p_[5])+(p_[6]+p_[7]))) \
      + (((p_[8]+p_[9])+(p_[10]+p_[11]))+((p_[12]+p_[13])+(p_[14]+p_[15]))); \
  uint32_t pa_, pb_, pc_, pd_; \
  asm("v_cvt_pk_bf16_f32 %0, %1, %2" : "=v"(pa_) : "v"(p_[0]), "v"(p_[1])); \
  asm("v_cvt_pk_bf16_f32 %0, %1, %2" : "=v"(pb_) : "v"(p_[2]), "v"(p_[3])); \
  asm("v_cvt_pk_bf16_f32 %0, %1, %2" : "=v"(pc_) : "v"(p_[4]), "v"(p_[5])); \
  asm("v_cvt_pk_bf16_f32 %0, %1, %2" : "=v"(pd_) : "v"(p_[6]), "v"(p_[7])); \
  PSWAP(pa_, pc_); PSWAP(pb_, pd_); \
  { u32x4 w_ = {pa_, pb_, pc_, pd_}; \
    __builtin_amdgcn_s_setprio(1); \
    O_ = __builtin_amdgcn_mfma_f32_32x32x16_bf16(V0_, __builtin_bit_cast(bf16x8, w_), O_, 0,0,0); \
    __builtin_amdgcn_s_setprio(0); } \
  asm("v_cvt_pk_bf16_f32 %0, %1, %2" : "=v"(pa_) : "v"(p_[8]),  "v"(p_[9])); \
  asm("v_cvt_pk_bf16_f32 %0, %1, %2" : "=v"(pb_) : "v"(p_[10]), "v"(p_[11])); \
  asm("v_cvt_pk_bf16_f32 %0, %1, %2" : "=v"(pc_) : "v"(p_[12]), "v"(p_[13])); \
  asm("v_cvt_pk_bf16_f32 %0, %1, %2" : "=v"(pd_) : "v"(p_[14]), "v"(p_[15])); \
  PSWAP(pa_, pc_); PSWAP(pb_, pd_); \
  { u32x4 w_ = {pa_, pb_, pc_, pd_}; \
    __builtin_amdgcn_s_setprio(1); \
    O_ = __builtin_amdgcn_mfma_f32_32x32x16_bf16(V1_, __builtin_bit_cast(bf16x8, w_), O_, 0,0,0); \
    __builtin_amdgcn_s_setprio(0); } \
} while(0)

__global__ __launch_bounds__(256, 2) void attn(
    const short* __restrict__ Qh, const short* __restrict__ Kh,
    const short* __restrict__ Vt, short* __restrict__ ctx)
{
  const int wid = threadIdx.x >> 6, lane = threadIdx.x & 63;
  const int l31 = lane & 31, hi8 = (lane >> 5)*8;
  const int bh = blockIdx.x;              // XCD = bh & 7 (32 % 8 == 0)
  const int q0 = blockIdx.y*128 + wid*32; // 4 q-tiles per block, same kv seq

  const short* Kb = Kh + (size_t)bh*SEQ*DH;
  const short* Vb = Vt + (size_t)bh*SEQ*DH;   // tiled layout

  const short* qp = Qh + ((size_t)bh*SEQ + q0 + l31)*DH + hi8;
  const bf16x8 Q0 = *(const bf16x8*)(qp);
  const bf16x8 Q1 = *(const bf16x8*)(qp + 16);

  f32x16 Oa = {}, Ob = {};
  float lrunA = 0.f, lrunB = 0.f;
  const f32x16 zf16 = {};

  bf16x8 Ka0,Ka1,Va0,Va1, Kc0,Kc1,Vc0,Vc1;
  LOADKV(Ka0,Ka1,Va0,Va1, 0);

  #pragma unroll 2
  for (int t = 0; t < 64; t += 2) {      // full kv sweep: 64 tiles of 32
    LOADKV(Kc0,Kc1,Vc0,Vc1, (t+1)*32);
    ATTN_TILE(Oa, lrunA, Ka0,Ka1,Va0,Va1);
    LOADKV(Ka0,Ka1,Va0,Va1, ((t+2)&63)*32);
    ATTN_TILE(Ob, lrunB, Kc0,Kc1,Vc0,Vc1);
  }

  float lrun = lrunA + lrunB;
  lrun += __shfl_xor(lrun, 32);          // both kv-row halves of this wave

  const float inv = 1.0f / lrun;
  // packed ctx: element (m, col=hh*32+dd) at WFRAG(m>>4, hh, dd>>3, m&15)+dd&7
  // lane holds q = l31, dd = rg*8 + (hi8>>1) + r  -> lg = rg, j0 = hi8>>1
  const int bb = bh >> 3, hh = bh & 7;
  const int mt8 = (((bb*SEQ) + q0 + l31) >> 4)*8 + hh;
  const int lrr = l31 & 15;
  const int j0  = hi8 >> 1;
  short* cp = ctx + (size_t)mt8*512;     // [4 lg][16 lr][8]
  #pragma unroll
  for (int rg=0; rg<4; ++rg) {
    s16x4 o;
    #pragma unroll
    for (int r=0;r<4;r++) o[r] = f2bf((Oa[rg*4+r] + Ob[rg*4+r])*inv);
    *(s16x4*)(cp + (rg*16 + lrr)*8 + j0) = o;
  }
}

// ---------------------------------------------------------------------------
// out = ctx @ Wo^T + bo; x = out + query; LayerNorm(x).
// SWAPPED mfma(Wo, ctx); BOTH operands fragment-packed (contiguous 1KB wave
// loads). float4 resid/bias/gamma/beta loads, float4 out stores.
// LN: in-lane sum + 2 shfl_xor + tiny LDS cross-wave exchange.
// ---------------------------------------------------------------------------
__global__ __launch_bounds__(256) void out_ln(
    const short* __restrict__ ctx, const short* __restrict__ Wob,
    const float* __restrict__ bo, const float* __restrict__ resid,
    const float* __restrict__ ln_g, const float* __restrict__ ln_b,
    float* __restrict__ out)
{
  __shared__ float2 red[4][16];
  const int wid = threadIdx.x >> 6, lane = threadIdx.x & 63;
  const int lr = lane & 15, lg = lane >> 4;
  const int m0 = blockIdx.x*16;
  const int c0 = wid*64;
  const int m  = m0 + lr;
  const int cb = c0 + lg*4;              // this lane's col base (per nf: +16)
  const int mt = m0 >> 4;

  // hoisted epilogue operands (vector loads, issued before the GEMM loop)
  float4 rs_[4], bo_[4], g_[4], b_[4];
  #pragma unroll
  for (int nf=0; nf<4; ++nf) {
    const int col = cb + nf*16;
    bo_[nf] = *(const float4*)(bo + col);
    g_[nf]  = *(const float4*)(ln_g + col);
    b_[nf]  = *(const float4*)(ln_b + col);
    rs_[nf] = *(const float4*)(resid + (size_t)m*DM + col);
  }
  __builtin_amdgcn_sched_barrier(0);

  f32x4 acc[4] = {};
  #pragma unroll
  for (int kc=0; kc<8; ++kc) {
    bf16x8 a = *(const bf16x8*)(ctx + WFRAG(mt, kc, lg, lr));
    #pragma unroll
    for (int nf=0; nf<4; ++nf) {
      bf16x8 b = *(const bf16x8*)(Wob + WFRAG(wid*4+nf, kc, lg, lr));
      acc[nf] = __builtin_amdgcn_mfma_f32_16x16x32_bf16(b, a, acc[nf], 0,0,0);
    }
  }

  // x = acc + bo + resid ; partial LN stats for row m over this wave's 64 cols
  float xv[4][4];
  float s = 0.f, s2 = 0.f;
  #pragma unroll
  for (int nf=0; nf<4; ++nf) {
    const float* bp = (const float*)&bo_[nf];
    const float* rp = (const float*)&rs_[nf];
    #pragma unroll
    for (int r=0;r<4;r++) {
      float v = acc[nf][r] + bp[r] + rp[r];
      xv[nf][r] = v; s += v; s2 += v*v;
    }
  }
  s  += __shfl_xor(s, 16);  s  += __shfl_xor(s, 32);
  s2 += __shfl_xor(s2, 16); s2 += __shfl_xor(s2, 32);
  if (lane < 16) red[wid][lr] = make_float2(s, s2);
  __syncthreads();
  s = 0.f; s2 = 0.f;
  #pragma unroll
  for (int w=0;w<4;w++){ float2 t = red[w][lr]; s += t.x; s2 += t.y; }
  const float mean = s * (1.0f/DM);
  const float var  = s2 * (1.0f/DM) - mean*mean;
  const float rstd = rsqrtf(var + 1e-5f);
  #pragma unroll
  for (int nf=0; nf<4; ++nf) {
    const float* gp = (const float*)&g_[nf];
    const float* bp = (const float*)&b_[nf];
    float4 o;
    o.x = (xv[nf][0]-mean)*rstd*gp[0] + bp[0];
    o.y = (xv[nf][1]-mean)*rstd*gp[1] + bp[1];
    o.z = (xv[nf][2]-mean)*rstd*gp[2] + bp[2];
    o.w = (xv[nf][3]-mean)*rstd*gp[3] + bp[3];
    *(float4*)(out + (size_t)m*DM + cb + nf*16) = o;
  }
}

extern "C" void kernel_launch(void* const* d_in, const int* in_sizes, int n_in,
                              void* d_out, int out_size, void* d_ws, size_t ws_size,
                              hipStream_t stream) {
  const float* query = (const float*)d_in[0];
  const float* key   = (const float*)d_in[1];
  const float* value = (const float*)d_in[2];
  const float* Wq    = (const float*)d_in[3];
  const float* bq    = (const float*)d_in[4];
  const float* Wk    = (const float*)d_in[5];
  const float* bk    = (const float*)d_in[6];
  const float* Wv    = (const float*)d_in[7];
  const float* bv    = (const float*)d_in[8];
  const float* Wo    = (const float*)d_in[9];
  const float* bo    = (const float*)d_in[10];
  const float* ln_g  = (const float*)d_in[11];
  const float* ln_b  = (const float*)d_in[12];
  float* out = (float*)d_out;

  const size_t HSZ = (size_t)NB*NHEADS*SEQ*DH;   // 2,097,152
  short* Qh  = (short*)d_ws;
  short* Kh  = Qh + HSZ;
  short* Vt  = Kh + HSZ;
  short* ctx = Vt + HSZ;                 // packed layout, same size
  short* Wqb = ctx + (size_t)MTOT*DM;
  short* Wkb = Wqb + DM*DM;
  short* Wvb = Wkb + DM*DM;
  short* Wob = Wvb + DM*DM;
  short* Xqp = Wob + DM*DM;              // packed X: 3 x 4MB
  short* Xkp = Xqp + (size_t)MTOT*DM;
  short* Xvp = Xkp + (size_t)MTOT*DM;    // total ws: ~29 MB (ws ~256MB)

  prep<<<dim3(128), 256, 0, stream>>>(Wq, Wk, Wv, Wo, Wqb, Wkb, Wvb, Wob);
  xprep<<<dim3(1024, 3), 256, 0, stream>>>(query, key, value, Xqp, Xkp, Xvp);
  qkv_proj<<<dim3(MTOT/32, 2, 3), 128, 0, stream>>>(
      Xqp, Xkp, Xvp, Wqb, Wkb, Wvb, bq, bk, bv, Qh, Kh, Vt);
  attn<<<dim3(NB*NHEADS, SEQ/128), 256, 0, stream>>>(Qh, Kh, Vt, ctx);
  out_ln<<<dim3(MTOT/16), 256, 0, stream>>>(ctx, Wob, bo, query, ln_g, ln_b, out);
}

// Round 23
// 67.061 us; speedup vs baseline: 1.0444x; 1.0444x over previous
//
#include <hip/hip_runtime.h>
#include <stdint.h>

#define DM 256
#define NHEADS 8
#define DH 32
#define SEQ 2048
#define NB 4
#define MTOT (NB*SEQ)

// scale * log2(e) : scores computed in exp2 domain
#define QSCALE 0.2550351270433207f

typedef __attribute__((ext_vector_type(8))) __bf16 bf16x8;
typedef __attribute__((ext_vector_type(4))) short s16x4;
typedef __attribute__((ext_vector_type(8))) short s16x8;
typedef __attribute__((ext_vector_type(4))) unsigned int u32x4;
typedef __attribute__((ext_vector_type(4))) float f32x4;
typedef __attribute__((ext_vector_type(16))) float f32x16;

__device__ inline short f2bf(float f){
  uint32_t u = __builtin_bit_cast(uint32_t, f);
  u += 0x7fffu + ((u >> 16) & 1u);
  return (short)(u >> 16);
}

// ---------------------------------------------------------------------------
// prep: fp32 weights -> bf16 (Wq scaled by QSCALE), PACKED fragment-
// contiguous: Wpack[nf][kc][lg][lr][8] — wave W-load = one 1KB block (r20
// win: -18.5us).
// ---------------------------------------------------------------------------
__global__ __launch_bounds__(256) void prep(
    const float* __restrict__ Wq, const float* __restrict__ Wk,
    const float* __restrict__ Wv, const float* __restrict__ Wo,
    short* __restrict__ Wqb, short* __restrict__ Wkb,
    short* __restrict__ Wvb, short* __restrict__ Wob)
{
  const int i = (blockIdx.x*256 + threadIdx.x)*8;
  const int seg = i >> 16;
  const int off = i & 65535;
  const float* src = seg==0?Wq: seg==1?Wk: seg==2?Wv:Wo;
  short* dst       = seg==0?Wqb: seg==1?Wkb: seg==2?Wvb:Wob;
  const float sc = (seg==0) ? QSCALE : 1.0f;
  float4 a = *(const float4*)(src + off);
  float4 b = *(const float4*)(src + off + 4);
  s16x8 o;
  o[0]=f2bf(a.x*sc); o[1]=f2bf(a.y*sc); o[2]=f2bf(a.z*sc); o[3]=f2bf(a.w*sc);
  o[4]=f2bf(b.x*sc); o[5]=f2bf(b.y*sc); o[6]=f2bf(b.z*sc); o[7]=f2bf(b.w*sc);
  // pack: row = off>>8, col = off&255 (col%8==0)
  const int row = off >> 8, col = off & 255;
  const int nf = row >> 4, lrr = row & 15;
  const int kc = col >> 5, lgg = (col >> 3) & 3;
  *(s16x8*)(dst + (((nf*8 + kc)*4 + lgg)*16 + lrr)*8) = o;
}

// fragment-packed W load offset for (global nf, kc, lg, lr)
#define WFRAG(nf_, kc_, lg_, lr_) (((((size_t)(nf_)*8 + (kc_))*4 + (lg_))*16 + (lr_))*8)

// ---------------------------------------------------------------------------
// QKV projection (r15 shape): bf16 packed W, n-split=2 (8 n-frags/wave),
// block = 2 waves x 16 rows, grid (MTOT/32, 2, 3).
// mode 0/1 (Q,K): SWAPPED mfma(W,X) -> s16x4 stores.
// mode 2 (V): original order, TILED [b,h][kv_tile][d=32][kv_in=32] layout.
// ---------------------------------------------------------------------------
__global__ __launch_bounds__(128) void qkv_proj(
    const float* __restrict__ Xq, const float* __restrict__ Xk, const float* __restrict__ Xv,
    const short* __restrict__ Wqb, const short* __restrict__ Wkb, const short* __restrict__ Wvb,
    const float* __restrict__ bq, const float* __restrict__ bk, const float* __restrict__ bv,
    short* __restrict__ Qh, short* __restrict__ Kh, short* __restrict__ Vt)
{
  const int mode = blockIdx.z;
  const float* X    = mode==0 ? Xq : (mode==1 ? Xk : Xv);
  const short* Wb   = mode==0 ? Wqb : (mode==1 ? Wkb : Wvb);
  const float* bias = mode==0 ? bq : (mode==1 ? bk : bv);
  short* dst        = mode==0 ? Qh : (mode==1 ? Kh : Vt);
  const float bscale = (mode==0) ? QSCALE : 1.0f;

  const int wid = threadIdx.x >> 6, lane = threadIdx.x & 63;
  const int lr = lane & 15, lg = lane >> 4;
  const int m0 = blockIdx.x*32 + wid*16;
  const int nf0 = blockIdx.y*8;

  f32x4 acc[8] = {};
  const int bb = m0 >> 11;

  if (mode < 2) {
    // ---- swapped: D[outcol][m], lane: m = m0+lr, cols = nf*16 + lg*4 + r
    #pragma unroll
    for (int kc = 0; kc < 8; ++kc) {
      const int k0 = kc*32 + lg*8;
      const float* ap = X + (size_t)(m0 + lr)*DM + k0;
      float4 a0 = *(const float4*)ap;
      float4 a1 = *(const float4*)(ap + 4);
      bf16x8 a;
      a[0]=(__bf16)a0.x; a[1]=(__bf16)a0.y; a[2]=(__bf16)a0.z; a[3]=(__bf16)a0.w;
      a[4]=(__bf16)a1.x; a[5]=(__bf16)a1.y; a[6]=(__bf16)a1.z; a[7]=(__bf16)a1.w;
      #pragma unroll
      for (int nfi=0; nfi<8; ++nfi) {
        bf16x8 b = *(const bf16x8*)(Wb + WFRAG(nf0+nfi, kc, lg, lr));
        acc[nfi] = __builtin_amdgcn_mfma_f32_16x16x32_bf16(b, a, acc[nfi], 0,0,0);
      }
    }
    const int m = m0 + lr;
    const int l = m & (SEQ-1);
    #pragma unroll
    for (int nfi=0; nfi<8; ++nfi) {
      const int colbase = (nf0+nfi)*16;
      const int h = colbase >> 5;
      const int dbase = (colbase & 31) + lg*4;
      float4 b4 = *(const float4*)(bias + colbase + lg*4);
      s16x4 pk;
      pk[0] = f2bf(acc[nfi][0] + b4.x*bscale);
      pk[1] = f2bf(acc[nfi][1] + b4.y*bscale);
      pk[2] = f2bf(acc[nfi][2] + b4.z*bscale);
      pk[3] = f2bf(acc[nfi][3] + b4.w*bscale);
      *(s16x4*)(dst + ((size_t)(bb*NHEADS + h)*SEQ + l)*DH + dbase) = pk;
    }
  } else {
    // ---- original: D[m][outcol], lane: col = nf*16+lr, rows = li0 + r
    #pragma unroll
    for (int kc = 0; kc < 8; ++kc) {
      const int k0 = kc*32 + lg*8;
      const float* ap = X + (size_t)(m0 + lr)*DM + k0;
      float4 a0 = *(const float4*)ap;
      float4 a1 = *(const float4*)(ap + 4);
      bf16x8 a;
      a[0]=(__bf16)a0.x; a[1]=(__bf16)a0.y; a[2]=(__bf16)a0.z; a[3]=(__bf16)a0.w;
      a[4]=(__bf16)a1.x; a[5]=(__bf16)a1.y; a[6]=(__bf16)a1.z; a[7]=(__bf16)a1.w;
      #pragma unroll
      for (int nfi=0; nfi<8; ++nfi) {
        bf16x8 b = *(const bf16x8*)(Wb + WFRAG(nf0+nfi, kc, lg, lr));
        acc[nfi] = __builtin_amdgcn_mfma_f32_16x16x32_bf16(a, b, acc[nfi], 0,0,0);
      }
    }
    const int li0 = (m0 & (SEQ-1)) + lg*4;
    #pragma unroll
    for (int nfi=0; nfi<8; ++nfi) {
      const int col = (nf0+nfi)*16 + lr;
      const float bv_ = bias[col];
      const int h = col >> 5, d = col & 31;
      s16x4 pk;
      #pragma unroll
      for (int r=0;r<4;r++) pk[r] = f2bf(acc[nfi][r] + bv_);
      *(s16x4*)(dst + (((size_t)(bb*NHEADS + h)*(SEQ/32) + (li0>>5))*DH + d)*32 + (li0&31)) = pk;
    }
  }
}

// ---------------------------------------------------------------------------
// Flash attention, 32x32x16 MFMA, swapped-QK, no max tracking, no kv-split
// (4 adjacent q-tiles share kv via L1). No LDS, no barriers. Dual
// accumulator chains (even/odd tiles), distance-1 prefetch, setprio around
// MFMA clusters. (r21 version — measured best.)
// ---------------------------------------------------------------------------
#if __has_builtin(__builtin_amdgcn_permlane32_swap)
typedef unsigned int u32x2v __attribute__((ext_vector_type(2)));
#define PSWAP(a_, b_) do { u32x2v r_ = __builtin_amdgcn_permlane32_swap((a_), (b_), false, false); (a_) = r_[0]; (b_) = r_[1]; } while(0)
#else
#define PSWAP(a_, b_) asm("s_nop 1\n\tv_permlane32_swap_b32 %0, %1" : "+v"(a_), "+v"(b_))
#endif

#define LOADKV(K0_,K1_,V0_,V1_, kvb_) do { \
  const short* kp_ = Kb + (size_t)((kvb_) + l31)*DH + hi8; \
  K0_ = *(const bf16x8*)kp_; K1_ = *(const bf16x8*)(kp_ + 16); \
  const short* vp_ = Vb + ((size_t)(((kvb_) >> 5)*32) + l31)*32 + hi8; \
  V0_ = *(const bf16x8*)vp_; V1_ = *(const bf16x8*)(vp_ + 16); \
} while(0)

#define ATTN_TILE(O_, l_, K0_, K1_, V0_, V1_) do { \
  __builtin_amdgcn_s_setprio(1); \
  f32x16 S_ = __builtin_amdgcn_mfma_f32_32x32x16_bf16(K0_, Q0, zf16, 0,0,0); \
  S_ = __builtin_amdgcn_mfma_f32_32x32x16_bf16(K1_, Q1, S_, 0,0,0); \
  __builtin_amdgcn_s_setprio(0); \
  float p_[16]; \
  _Pragma("unroll") for (int r_=0;r_<16;r_++) p_[r_] = __builtin_amdgcn_exp2f(S_[r_]); \
  l_ += (((p_[0]+p_[1])+(p_[2]+p_[3]))+((p_[4]+p_[5])+(p_[6]+p_[7]))) \
      + (((p_[8]+p_[9])+(p_[10]+p_[11]))+((p_[12]+p_[13])+(p_[14]+p_[15]))); \
  uint32_t pa_, pb_, pc_, pd_; \
  asm("v_cvt_pk_bf16_f32 %0, %1, %2" : "=v"(pa_) : "v"(p_[0]), "v"(p_[1])); \
  asm("v_cvt_pk_bf16_f32 %0, %1, %2" : "=v"(pb_) : "v"(p_[2]), "v"(p_[3])); \
  asm("v_cvt_pk_bf16_f32 %0, %1, %2" : "=v"(pc_) : "v"(p_[4]), "v"(p_[5])); \
  asm("v_cvt_pk_bf16_f32 %0, %1, %2" : "=v"(pd_) : "v"(p_[6]), "v"(p_[7])); \
  PSWAP(pa_, pc_); PSWAP(pb_, pd_); \
  { u32x4 w_ = {pa_, pb_, pc_, pd_}; \
    __builtin_amdgcn_s_setprio(1); \
    O_ = __builtin_amdgcn_mfma_f32_32x32x16_bf16(V0_, __builtin_bit_cast(bf16x8, w_), O_, 0,0,0); \
    __builtin_amdgcn_s_setprio(0); } \
  asm("v_cvt_pk_bf16_f32 %0, %1, %2" : "=v"(pa_) : "v"(p_[8]),  "v"(p_[9])); \
  asm("v_cvt_pk_bf16_f32 %0, %1, %2" : "=v"(pb_) : "v"(p_[10]), "v"(p_[11])); \
  asm("v_cvt_pk_bf16_f32 %0, %1, %2" : "=v"(pc_) : "v"(p_[12]), "v"(p_[13])); \
  asm("v_cvt_pk_bf16_f32 %0, %1, %2" : "=v"(pd_) : "v"(p_[14]), "v"(p_[15])); \
  PSWAP(pa_, pc_); PSWAP(pb_, pd_); \
  { u32x4 w_ = {pa_, pb_, pc_, pd_}; \
    __builtin_amdgcn_s_setprio(1); \
    O_ = __builtin_amdgcn_mfma_f32_32x32x16_bf16(V1_, __builtin_bit_cast(bf16x8, w_), O_, 0,0,0); \
    __builtin_amdgcn_s_setprio(0); } \
} while(0)

__global__ __launch_bounds__(256, 2) void attn(
    const short* __restrict__ Qh, const short* __restrict__ Kh,
    const short* __restrict__ Vt, short* __restrict__ ctx)
{
  const int wid = threadIdx.x >> 6, lane = threadIdx.x & 63;
  const int l31 = lane & 31, hi8 = (lane >> 5)*8;
  const int bh = blockIdx.x;              // XCD = bh & 7 (32 % 8 == 0)
  const int q0 = blockIdx.y*128 + wid*32; // 4 q-tiles per block, same kv seq

  const short* Kb = Kh + (size_t)bh*SEQ*DH;
  const short* Vb = Vt + (size_t)bh*SEQ*DH;   // tiled layout

  const short* qp = Qh + ((size_t)bh*SEQ + q0 + l31)*DH + hi8;
  const bf16x8 Q0 = *(const bf16x8*)(qp);
  const bf16x8 Q1 = *(const bf16x8*)(qp + 16);

  f32x16 Oa = {}, Ob = {};
  float lrunA = 0.f, lrunB = 0.f;
  const f32x16 zf16 = {};

  bf16x8 Ka0,Ka1,Va0,Va1, Kc0,Kc1,Vc0,Vc1;
  LOADKV(Ka0,Ka1,Va0,Va1, 0);

  #pragma unroll 2
  for (int t = 0; t < 64; t += 2) {      // full kv sweep: 64 tiles of 32
    LOADKV(Kc0,Kc1,Vc0,Vc1, (t+1)*32);
    ATTN_TILE(Oa, lrunA, Ka0,Ka1,Va0,Va1);
    LOADKV(Ka0,Ka1,Va0,Va1, ((t+2)&63)*32);
    ATTN_TILE(Ob, lrunB, Kc0,Kc1,Vc0,Vc1);
  }

  float lrun = lrunA + lrunB;
  lrun += __shfl_xor(lrun, 32);          // both kv-row halves of this wave

  const float inv = 1.0f / lrun;
  // O^T lane layout: q = l31, d = (reg&3) + 8*(reg>>2) + (hi8>>1)
  const int bb = bh >> 3, hh = bh & 7;
  short* cp = ctx + ((size_t)(bb*SEQ) + q0 + l31)*DM + hh*DH + (hi8 >> 1);
  #pragma unroll
  for (int rg=0; rg<4; ++rg) {
    s16x4 o;
    #pragma unroll
    for (int r=0;r<4;r++) o[r] = f2bf((Oa[rg*4+r] + Ob[rg*4+r])*inv);
    *(s16x4*)(cp + rg*8) = o;
  }
}

// ---------------------------------------------------------------------------
// out = ctx @ Wo^T + bo; x = out + query; LayerNorm(x).
// SWAPPED mfma(Wo, ctx) with PACKED Wo fragments (contiguous 1KB per wave
// load). float4 resid/bias/gamma/beta loads, float4 out stores.
// LN: in-lane sum + 2 shfl_xor + tiny LDS cross-wave exchange.
// ---------------------------------------------------------------------------
__global__ __launch_bounds__(256) void out_ln(
    const short* __restrict__ ctx, const short* __restrict__ Wob,
    const float* __restrict__ bo, const float* __restrict__ resid,
    const float* __restrict__ ln_g, const float* __restrict__ ln_b,
    float* __restrict__ out)
{
  __shared__ float2 red[4][16];
  const int wid = threadIdx.x >> 6, lane = threadIdx.x & 63;
  const int lr = lane & 15, lg = lane >> 4;
  const int m0 = blockIdx.x*16;
  const int c0 = wid*64;
  const int m  = m0 + lr;
  const int cb = c0 + lg*4;              // this lane's col base (per nf: +16)

  // hoisted epilogue operands (vector loads, issued before the GEMM loop)
  float4 rs_[4], bo_[4], g_[4], b_[4];
  #pragma unroll
  for (int nf=0; nf<4; ++nf) {
    const int col = cb + nf*16;
    bo_[nf] = *(const float4*)(bo + col);
    g_[nf]  = *(const float4*)(ln_g + col);
    b_[nf]  = *(const float4*)(ln_b + col);
    rs_[nf] = *(const float4*)(resid + (size_t)m*DM + col);
  }
  __builtin_amdgcn_sched_barrier(0);

  f32x4 acc[4] = {};
  #pragma unroll
  for (int kc=0; kc<8; ++kc) {
    const int k0 = kc*32 + lg*8;
    bf16x8 a = *(const bf16x8*)(ctx + (size_t)(m0 + lr)*DM + k0);
    #pragma unroll
    for (int nf=0; nf<4; ++nf) {
      bf16x8 b = *(const bf16x8*)(Wob + WFRAG(wid*4+nf, kc, lg, lr));
      acc[nf] = __builtin_amdgcn_mfma_f32_16x16x32_bf16(b, a, acc[nf], 0,0,0);
    }
  }

  // x = acc + bo + resid ; partial LN stats for row m over this wave's 64 cols
  float xv[4][4];
  float s = 0.f, s2 = 0.f;
  #pragma unroll
  for (int nf=0; nf<4; ++nf) {
    const float* bp = (const float*)&bo_[nf];
    const float* rp = (const float*)&rs_[nf];
    #pragma unroll
    for (int r=0;r<4;r++) {
      float v = acc[nf][r] + bp[r] + rp[r];
      xv[nf][r] = v; s += v; s2 += v*v;
    }
  }
  s  += __shfl_xor(s, 16);  s  += __shfl_xor(s, 32);
  s2 += __shfl_xor(s2, 16); s2 += __shfl_xor(s2, 32);
  if (lane < 16) red[wid][lr] = make_float2(s, s2);
  __syncthreads();
  s = 0.f; s2 = 0.f;
  #pragma unroll
  for (int w=0;w<4;w++){ float2 t = red[w][lr]; s += t.x; s2 += t.y; }
  const float mean = s * (1.0f/DM);
  const float var  = s2 * (1.0f/DM) - mean*mean;
  const float rstd = rsqrtf(var + 1e-5f);
  #pragma unroll
  for (int nf=0; nf<4; ++nf) {
    const float* gp = (const float*)&g_[nf];
    const float* bp = (const float*)&b_[nf];
    float4 o;
    o.x = (xv[nf][0]-mean)*rstd*gp[0] + bp[0];
    o.y = (xv[nf][1]-mean)*rstd*gp[1] + bp[1];
    o.z = (xv[nf][2]-mean)*rstd*gp[2] + bp[2];
    o.w = (xv[nf][3]-mean)*rstd*gp[3] + bp[3];
    *(float4*)(out + (size_t)m*DM + cb + nf*16) = o;
  }
}

extern "C" void kernel_launch(void* const* d_in, const int* in_sizes, int n_in,
                              void* d_out, int out_size, void* d_ws, size_t ws_size,
                              hipStream_t stream) {
  const float* query = (const float*)d_in[0];
  const float* key   = (const float*)d_in[1];
  const float* value = (const float*)d_in[2];
  const float* Wq    = (const float*)d_in[3];
  const float* bq    = (const float*)d_in[4];
  const float* Wk    = (const float*)d_in[5];
  const float* bk    = (const float*)d_in[6];
  const float* Wv    = (const float*)d_in[7];
  const float* bv    = (const float*)d_in[8];
  const float* Wo    = (const float*)d_in[9];
  const float* bo    = (const float*)d_in[10];
  const float* ln_g  = (const float*)d_in[11];
  const float* ln_b  = (const float*)d_in[12];
  float* out = (float*)d_out;

  const size_t HSZ = (size_t)NB*NHEADS*SEQ*DH;   // 2,097,152
  short* Qh  = (short*)d_ws;
  short* Kh  = Qh + HSZ;
  short* Vt  = Kh + HSZ;
  short* ctx = Vt + HSZ;
  short* Wqb = ctx + (size_t)MTOT*DM;
  short* Wkb = Wqb + DM*DM;
  short* Wvb = Wkb + DM*DM;
  short* Wob = Wvb + DM*DM;   // total ws: ~17 MB

  prep<<<dim3(128), 256, 0, stream>>>(Wq, Wk, Wv, Wo, Wqb, Wkb, Wvb, Wob);
  qkv_proj<<<dim3(MTOT/32, 2, 3), 128, 0, stream>>>(
      query, key, value, Wqb, Wkb, Wvb, bq, bk, bv, Qh, Kh, Vt);
  attn<<<dim3(NB*NHEADS, SEQ/128), 256, 0, stream>>>(Qh, Kh, Vt, ctx);
  out_ln<<<dim3(MTOT/16), 256, 0, stream>>>(ctx, Wob, bo, query, ln_g, ln_b, out);
}

// Round 25
// 66.268 us; speedup vs baseline: 1.0569x; 1.0120x over previous
//
#include <hip/hip_runtime.h>
#include <stdint.h>

#define DM 256
#define NHEADS 8
#define DH 32
#define SEQ 2048
#define NB 4
#define MTOT (NB*SEQ)

// scale * log2(e) : scores computed in exp2 domain
#define QSCALE 0.2550351270433207f

typedef __attribute__((ext_vector_type(8))) __bf16 bf16x8;
typedef __attribute__((ext_vector_type(4))) short s16x4;
typedef __attribute__((ext_vector_type(8))) short s16x8;
typedef __attribute__((ext_vector_type(4))) unsigned int u32x4;
typedef __attribute__((ext_vector_type(4))) float f32x4;
typedef __attribute__((ext_vector_type(16))) float f32x16;

__device__ inline short f2bf(float f){
  uint32_t u = __builtin_bit_cast(uint32_t, f);
  u += 0x7fffu + ((u >> 16) & 1u);
  return (short)(u >> 16);
}

// fragment-packed offset for ([16-row tile] t, kc, lg, lr): one contiguous
// 1KB block per wave fragment-load.
#define WFRAG(t_, kc_, lg_, lr_) (((((size_t)(t_)*8 + (kc_))*4 + (lg_))*16 + (lr_))*8)

// ---------------------------------------------------------------------------
// prep: fp32 weights -> bf16 (Wq scaled by QSCALE), fragment-packed (r20
// win: -18.5us).
// ---------------------------------------------------------------------------
__global__ __launch_bounds__(256) void prep(
    const float* __restrict__ Wq, const float* __restrict__ Wk,
    const float* __restrict__ Wv, const float* __restrict__ Wo,
    short* __restrict__ Wqb, short* __restrict__ Wkb,
    short* __restrict__ Wvb, short* __restrict__ Wob)
{
  const int i = (blockIdx.x*256 + threadIdx.x)*8;
  const int seg = i >> 16;
  const int off = i & 65535;
  const float* src = seg==0?Wq: seg==1?Wk: seg==2?Wv:Wo;
  short* dst       = seg==0?Wqb: seg==1?Wkb: seg==2?Wvb:Wob;
  const float sc = (seg==0) ? QSCALE : 1.0f;
  float4 a = *(const float4*)(src + off);
  float4 b = *(const float4*)(src + off + 4);
  s16x8 o;
  o[0]=f2bf(a.x*sc); o[1]=f2bf(a.y*sc); o[2]=f2bf(a.z*sc); o[3]=f2bf(a.w*sc);
  o[4]=f2bf(b.x*sc); o[5]=f2bf(b.y*sc); o[6]=f2bf(b.z*sc); o[7]=f2bf(b.w*sc);
  const int row = off >> 8, col = off & 255;
  *(s16x8*)(dst + WFRAG(row>>4, col>>5, (col>>3)&3, row&15)) = o;
}

// ---------------------------------------------------------------------------
// QKV projection (r15 shape): bf16 packed W, n-split=2 (8 n-frags/wave),
// block = 2 waves x 16 rows, grid (MTOT/32, 2, 3).
// mode 0/1 (Q,K): SWAPPED mfma(W,X) -> s16x4 stores.
// mode 2 (V): original order, TILED [b,h][kv_tile][d=32][kv_in=32] layout.
// ---------------------------------------------------------------------------
__global__ __launch_bounds__(128) void qkv_proj(
    const float* __restrict__ Xq, const float* __restrict__ Xk, const float* __restrict__ Xv,
    const short* __restrict__ Wqb, const short* __restrict__ Wkb, const short* __restrict__ Wvb,
    const float* __restrict__ bq, const float* __restrict__ bk, const float* __restrict__ bv,
    short* __restrict__ Qh, short* __restrict__ Kh, short* __restrict__ Vt)
{
  const int mode = blockIdx.z;
  const float* X    = mode==0 ? Xq : (mode==1 ? Xk : Xv);
  const short* Wb   = mode==0 ? Wqb : (mode==1 ? Wkb : Wvb);
  const float* bias = mode==0 ? bq : (mode==1 ? bk : bv);
  short* dst        = mode==0 ? Qh : (mode==1 ? Kh : Vt);
  const float bscale = (mode==0) ? QSCALE : 1.0f;

  const int wid = threadIdx.x >> 6, lane = threadIdx.x & 63;
  const int lr = lane & 15, lg = lane >> 4;
  const int m0 = blockIdx.x*32 + wid*16;
  const int nf0 = blockIdx.y*8;

  f32x4 acc[8] = {};
  const int bb = m0 >> 11;

  if (mode < 2) {
    // ---- swapped: D[outcol][m], lane: m = m0+lr, cols = nf*16 + lg*4 + r
    #pragma unroll
    for (int kc = 0; kc < 8; ++kc) {
      const int k0 = kc*32 + lg*8;
      const float* ap = X + (size_t)(m0 + lr)*DM + k0;
      float4 a0 = *(const float4*)ap;
      float4 a1 = *(const float4*)(ap + 4);
      bf16x8 a;
      a[0]=(__bf16)a0.x; a[1]=(__bf16)a0.y; a[2]=(__bf16)a0.z; a[3]=(__bf16)a0.w;
      a[4]=(__bf16)a1.x; a[5]=(__bf16)a1.y; a[6]=(__bf16)a1.z; a[7]=(__bf16)a1.w;
      #pragma unroll
      for (int nfi=0; nfi<8; ++nfi) {
        bf16x8 b = *(const bf16x8*)(Wb + WFRAG(nf0+nfi, kc, lg, lr));
        acc[nfi] = __builtin_amdgcn_mfma_f32_16x16x32_bf16(b, a, acc[nfi], 0,0,0);
      }
    }
    const int m = m0 + lr;
    const int l = m & (SEQ-1);
    #pragma unroll
    for (int nfi=0; nfi<8; ++nfi) {
      const int colbase = (nf0+nfi)*16;
      const int h = colbase >> 5;
      const int dbase = (colbase & 31) + lg*4;
      float4 b4 = *(const float4*)(bias + colbase + lg*4);
      s16x4 pk;
      pk[0] = f2bf(acc[nfi][0] + b4.x*bscale);
      pk[1] = f2bf(acc[nfi][1] + b4.y*bscale);
      pk[2] = f2bf(acc[nfi][2] + b4.z*bscale);
      pk[3] = f2bf(acc[nfi][3] + b4.w*bscale);
      *(s16x4*)(dst + ((size_t)(bb*NHEADS + h)*SEQ + l)*DH + dbase) = pk;
    }
  } else {
    // ---- original: D[m][outcol], lane: col = nf*16+lr, rows = li0 + r
    #pragma unroll
    for (int kc = 0; kc < 8; ++kc) {
      const int k0 = kc*32 + lg*8;
      const float* ap = X + (size_t)(m0 + lr)*DM + k0;
      float4 a0 = *(const float4*)ap;
      float4 a1 = *(const float4*)(ap + 4);
      bf16x8 a;
      a[0]=(__bf16)a0.x; a[1]=(__bf16)a0.y; a[2]=(__bf16)a0.z; a[3]=(__bf16)a0.w;
      a[4]=(__bf16)a1.x; a[5]=(__bf16)a1.y; a[6]=(__bf16)a1.z; a[7]=(__bf16)a1.w;
      #pragma unroll
      for (int nfi=0; nfi<8; ++nfi) {
        bf16x8 b = *(const bf16x8*)(Wb + WFRAG(nf0+nfi, kc, lg, lr));
        acc[nfi] = __builtin_amdgcn_mfma_f32_16x16x32_bf16(a, b, acc[nfi], 0,0,0);
      }
    }
    const int li0 = (m0 & (SEQ-1)) + lg*4;
    #pragma unroll
    for (int nfi=0; nfi<8; ++nfi) {
      const int col = (nf0+nfi)*16 + lr;
      const float bv_ = bias[col];
      const int h = col >> 5, d = col & 31;
      s16x4 pk;
      #pragma unroll
      for (int r=0;r<4;r++) pk[r] = f2bf(acc[nfi][r] + bv_);
      *(s16x4*)(dst + (((size_t)(bb*NHEADS + h)*(SEQ/32) + (li0>>5))*DH + d)*32 + (li0&31)) = pk;
    }
  }
}

// ---------------------------------------------------------------------------
// Flash attention (r21 loop): 32x32x16 MFMA, swapped-QK, no max tracking,
// no kv-split (4 adjacent q-tiles share kv via L1), no LDS, no barriers,
// dual accumulator chains, distance-1 prefetch, setprio.
// ctx written FRAGMENT-PACKED (verified r22): removes the 512B-stride exit
// scatter and makes out_ln's A-load contiguous.
// ---------------------------------------------------------------------------
#if __has_builtin(__builtin_amdgcn_permlane32_swap)
typedef unsigned int u32x2v __attribute__((ext_vector_type(2)));
#define PSWAP(a_, b_) do { u32x2v r_ = __builtin_amdgcn_permlane32_swap((a_), (b_), false, false); (a_) = r_[0]; (b_) = r_[1]; } while(0)
#else
#define PSWAP(a_, b_) asm("s_nop 1\n\tv_permlane32_swap_b32 %0, %1" : "+v"(a_), "+v"(b_))
#endif

#define LOADKV(K0_,K1_,V0_,V1_, kvb_) do { \
  const short* kp_ = Kb + (size_t)((kvb_) + l31)*DH + hi8; \
  K0_ = *(const bf16x8*)kp_; K1_ = *(const bf16x8*)(kp_ + 16); \
  const short* vp_ = Vb + ((size_t)(((kvb_) >> 5)*32) + l31)*32 + hi8; \
  V0_ = *(const bf16x8*)vp_; V1_ = *(const bf16x8*)(vp_ + 16); \
} while(0)

#define ATTN_TILE(O_, l_, K0_, K1_, V0_, V1_) do { \
  __builtin_amdgcn_s_setprio(1); \
  f32x16 S_ = __builtin_amdgcn_mfma_f32_32x32x16_bf16(K0_, Q0, zf16, 0,0,0); \
  S_ = __builtin_amdgcn_mfma_f32_32x32x16_bf16(K1_, Q1, S_, 0,0,0); \
  __builtin_amdgcn_s_setprio(0); \
  float p_[16]; \
  _Pragma("unroll") for (int r_=0;r_<16;r_++) p_[r_] = __builtin_amdgcn_exp2f(S_[r_]); \
  l_ += (((p_[0]+p_[1])+(p_[2]+p_[3]))+((p_[4]+p_[5])+(p_[6]+p_[7]))) \
      + (((p_[8]+p_[9])+(p_[10]+p_[11]))+((p_[12]+p_[13])+(p_[14]+p_[15]))); \
  uint32_t pa_, pb_, pc_, pd_; \
  asm("v_cvt_pk_bf16_f32 %0, %1, %2" : "=v"(pa_) : "v"(p_[0]), "v"(p_[1])); \
  asm("v_cvt_pk_bf16_f32 %0, %1, %2" : "=v"(pb_) : "v"(p_[2]), "v"(p_[3])); \
  asm("v_cvt_pk_bf16_f32 %0, %1, %2" : "=v"(pc_) : "v"(p_[4]), "v"(p_[5])); \
  asm("v_cvt_pk_bf16_f32 %0, %1, %2" : "=v"(pd_) : "v"(p_[6]), "v"(p_[7])); \
  PSWAP(pa_, pc_); PSWAP(pb_, pd_); \
  { u32x4 w_ = {pa_, pb_, pc_, pd_}; \
    __builtin_amdgcn_s_setprio(1); \
    O_ = __builtin_amdgcn_mfma_f32_32x32x16_bf16(V0_, __builtin_bit_cast(bf16x8, w_), O_, 0,0,0); \
    __builtin_amdgcn_s_setprio(0); } \
  asm("v_cvt_pk_bf16_f32 %0, %1, %2" : "=v"(pa_) : "v"(p_[8]),  "v"(p_[9])); \
  asm("v_cvt_pk_bf16_f32 %0, %1, %2" : "=v"(pb_) : "v"(p_[10]), "v"(p_[11])); \
  asm("v_cvt_pk_bf16_f32 %0, %1, %2" : "=v"(pc_) : "v"(p_[12]), "v"(p_[13])); \
  asm("v_cvt_pk_bf16_f32 %0, %1, %2" : "=v"(pd_) : "v"(p_[14]), "v"(p_[15])); \
  PSWAP(pa_, pc_); PSWAP(pb_, pd_); \
  { u32x4 w_ = {pa_, pb_, pc_, pd_}; \
    __builtin_amdgcn_s_setprio(1); \
    O_ = __builtin_amdgcn_mfma_f32_32x32x16_bf16(V1_, __builtin_bit_cast(bf16x8, w_), O_, 0,0,0); \
    __builtin_amdgcn_s_setprio(0); } \
} while(0)

__global__ __launch_bounds__(256, 2) void attn(
    const short* __restrict__ Qh, const short* __restrict__ Kh,
    const short* __restrict__ Vt, short* __restrict__ ctx)
{
  const int wid = threadIdx.x >> 6, lane = threadIdx.x & 63;
  const int l31 = lane & 31, hi8 = (lane >> 5)*8;
  const int bh = blockIdx.x;              // XCD = bh & 7 (32 % 8 == 0)
  const int q0 = blockIdx.y*128 + wid*32; // 4 q-tiles per block, same kv seq

  const short* Kb = Kh + (size_t)bh*SEQ*DH;
  const short* Vb = Vt + (size_t)bh*SEQ*DH;   // tiled layout

  const short* qp = Qh + ((size_t)bh*SEQ + q0 + l31)*DH + hi8;
  const bf16x8 Q0 = *(const bf16x8*)(qp);
  const bf16x8 Q1 = *(const bf16x8*)(qp + 16);

  f32x16 Oa = {}, Ob = {};
  float lrunA = 0.f, lrunB = 0.f;
  const f32x16 zf16 = {};

  bf16x8 Ka0,Ka1,Va0,Va1, Kc0,Kc1,Vc0,Vc1;
  LOADKV(Ka0,Ka1,Va0,Va1, 0);

  #pragma unroll 2
  for (int t = 0; t < 64; t += 2) {      // full kv sweep: 64 tiles of 32
    LOADKV(Kc0,Kc1,Vc0,Vc1, (t+1)*32);
    ATTN_TILE(Oa, lrunA, Ka0,Ka1,Va0,Va1);
    LOADKV(Ka0,Ka1,Va0,Va1, ((t+2)&63)*32);
    ATTN_TILE(Ob, lrunB, Kc0,Kc1,Vc0,Vc1);
  }

  float lrun = lrunA + lrunB;
  lrun += __shfl_xor(lrun, 32);          // both kv-row halves of this wave

  const float inv = 1.0f / lrun;
  // packed ctx (verified r22): elem (m, col=hh*32+dd) at
  // WFRAG(m>>4, hh, dd>>3, m&15) + (dd&7); lane: q=l31, dd = rg*8 + j0 + r
  const int bb = bh >> 3, hh = bh & 7;
  const int mt8 = (((bb*SEQ) + q0 + l31) >> 4)*8 + hh;
  const int lrr = l31 & 15;
  const int j0  = hi8 >> 1;
  short* cp = ctx + (size_t)mt8*512;     // [4 lg][16 lr][8]
  #pragma unroll
  for (int rg=0; rg<4; ++rg) {
    s16x4 o;
    #pragma unroll
    for (int r=0;r<4;r++) o[r] = f2bf((Oa[rg*4+r] + Ob[rg*4+r])*inv);
    *(s16x4*)(cp + (rg*16 + lrr)*8 + j0) = o;
  }
}

// ---------------------------------------------------------------------------
// out = ctx @ Wo^T + bo; x = out + query; LayerNorm(x).
// SWAPPED mfma(Wo, ctx); BOTH operands fragment-packed (contiguous 1KB wave
// loads). float4 resid/bias/gamma/beta loads, float4 out stores.
// LN: in-lane sum + 2 shfl_xor + tiny LDS cross-wave exchange.
// ---------------------------------------------------------------------------
__global__ __launch_bounds__(256) void out_ln(
    const short* __restrict__ ctx, const short* __restrict__ Wob,
    const float* __restrict__ bo, const float* __restrict__ resid,
    const float* __restrict__ ln_g, const float* __restrict__ ln_b,
    float* __restrict__ out)
{
  __shared__ float2 red[4][16];
  const int wid = threadIdx.x >> 6, lane = threadIdx.x & 63;
  const int lr = lane & 15, lg = lane >> 4;
  const int m0 = blockIdx.x*16;
  const int c0 = wid*64;
  const int m  = m0 + lr;
  const int cb = c0 + lg*4;              // this lane's col base (per nf: +16)
  const int mt = m0 >> 4;

  // hoisted epilogue operands (vector loads, issued before the GEMM loop)
  float4 rs_[4], bo_[4], g_[4], b_[4];
  #pragma unroll
  for (int nf=0; nf<4; ++nf) {
    const int col = cb + nf*16;
    bo_[nf] = *(const float4*)(bo + col);
    g_[nf]  = *(const float4*)(ln_g + col);
    b_[nf]  = *(const float4*)(ln_b + col);
    rs_[nf] = *(const float4*)(resid + (size_t)m*DM + col);
  }
  __builtin_amdgcn_sched_barrier(0);

  f32x4 acc[4] = {};
  #pragma unroll
  for (int kc=0; kc<8; ++kc) {
    bf16x8 a = *(const bf16x8*)(ctx + WFRAG(mt, kc, lg, lr));
    #pragma unroll
    for (int nf=0; nf<4; ++nf) {
      bf16x8 b = *(const bf16x8*)(Wob + WFRAG(wid*4+nf, kc, lg, lr));
      acc[nf] = __builtin_amdgcn_mfma_f32_16x16x32_bf16(b, a, acc[nf], 0,0,0);
    }
  }

  // x = acc + bo + resid ; partial LN stats for row m over this wave's 64 cols
  float xv[4][4];
  float s = 0.f, s2 = 0.f;
  #pragma unroll
  for (int nf=0; nf<4; ++nf) {
    const float* bp = (const float*)&bo_[nf];
    const float* rp = (const float*)&rs_[nf];
    #pragma unroll
    for (int r=0;r<4;r++) {
      float v = acc[nf][r] + bp[r] + rp[r];
      xv[nf][r] = v; s += v; s2 += v*v;
    }
  }
  s  += __shfl_xor(s, 16);  s  += __shfl_xor(s, 32);
  s2 += __shfl_xor(s2, 16); s2 += __shfl_xor(s2, 32);
  if (lane < 16) red[wid][lr] = make_float2(s, s2);
  __syncthreads();
  s = 0.f; s2 = 0.f;
  #pragma unroll
  for (int w=0;w<4;w++){ float2 t = red[w][lr]; s += t.x; s2 += t.y; }
  const float mean = s * (1.0f/DM);
  const float var  = s2 * (1.0f/DM) - mean*mean;
  const float rstd = rsqrtf(var + 1e-5f);
  #pragma unroll
  for (int nf=0; nf<4; ++nf) {
    const float* gp = (const float*)&g_[nf];
    const float* bp = (const float*)&b_[nf];
    float4 o;
    o.x = (xv[nf][0]-mean)*rstd*gp[0] + bp[0];
    o.y = (xv[nf][1]-mean)*rstd*gp[1] + bp[1];
    o.z = (xv[nf][2]-mean)*rstd*gp[2] + bp[2];
    o.w = (xv[nf][3]-mean)*rstd*gp[3] + bp[3];
    *(float4*)(out + (size_t)m*DM + cb + nf*16) = o;
  }
}

extern "C" void kernel_launch(void* const* d_in, const int* in_sizes, int n_in,
                              void* d_out, int out_size, void* d_ws, size_t ws_size,
                              hipStream_t stream) {
  const float* query = (const float*)d_in[0];
  const float* key   = (const float*)d_in[1];
  const float* value = (const float*)d_in[2];
  const float* Wq    = (const float*)d_in[3];
  const float* bq    = (const float*)d_in[4];
  const float* Wk    = (const float*)d_in[5];
  const float* bk    = (const float*)d_in[6];
  const float* Wv    = (const float*)d_in[7];
  const float* bv    = (const float*)d_in[8];
  const float* Wo    = (const float*)d_in[9];
  const float* bo    = (const float*)d_in[10];
  const float* ln_g  = (const float*)d_in[11];
  const float* ln_b  = (const float*)d_in[12];
  float* out = (float*)d_out;

  const size_t HSZ = (size_t)NB*NHEADS*SEQ*DH;   // 2,097,152
  short* Qh  = (short*)d_ws;
  short* Kh  = Qh + HSZ;
  short* Vt  = Kh + HSZ;
  short* ctx = Vt + HSZ;                 // packed layout, same size
  short* Wqb = ctx + (size_t)MTOT*DM;
  short* Wkb = Wqb + DM*DM;
  short* Wvb = Wkb + DM*DM;
  short* Wob = Wvb + DM*DM;   // total ws: ~17 MB

  prep<<<dim3(128), 256, 0, stream>>>(Wq, Wk, Wv, Wo, Wqb, Wkb, Wvb, Wob);
  qkv_proj<<<dim3(MTOT/32, 2, 3), 128, 0, stream>>>(
      query, key, value, Wqb, Wkb, Wvb, bq, bk, bv, Qh, Kh, Vt);
  attn<<<dim3(NB*NHEADS, SEQ/128), 256, 0, stream>>>(Qh, Kh, Vt, ctx);
  out_ln<<<dim3(MTOT/16), 256, 0, stream>>>(ctx, Wob, bo, query, ln_g, ln_b, out);
}

// Round 26
// 66.012 us; speedup vs baseline: 1.0610x; 1.0039x over previous
//
#include <hip/hip_runtime.h>
#include <stdint.h>

#define DM 256
#define NHEADS 8
#define DH 32
#define SEQ 2048
#define NB 4
#define MTOT (NB*SEQ)

// scale * log2(e) : scores computed in exp2 domain
#define QSCALE 0.2550351270433207f

typedef __attribute__((ext_vector_type(8))) __bf16 bf16x8;
typedef __attribute__((ext_vector_type(4))) short s16x4;
typedef __attribute__((ext_vector_type(8))) short s16x8;
typedef __attribute__((ext_vector_type(4))) unsigned int u32x4;
typedef __attribute__((ext_vector_type(4))) float f32x4;
typedef __attribute__((ext_vector_type(16))) float f32x16;

__device__ inline short f2bf(float f){
  uint32_t u = __builtin_bit_cast(uint32_t, f);
  u += 0x7fffu + ((u >> 16) & 1u);
  return (short)(u >> 16);
}

// fragment-packed offset for ([16-row tile] t, kc, lg, lr): one contiguous
// 1KB block per wave fragment-load.
#define WFRAG(t_, kc_, lg_, lr_) (((((size_t)(t_)*8 + (kc_))*4 + (lg_))*16 + (lr_))*8)

// ---------------------------------------------------------------------------
// prep: fp32 weights -> bf16 (Wq scaled by QSCALE), fragment-packed (r20
// win: -18.5us).
// ---------------------------------------------------------------------------
__global__ __launch_bounds__(256) void prep(
    const float* __restrict__ Wq, const float* __restrict__ Wk,
    const float* __restrict__ Wv, const float* __restrict__ Wo,
    short* __restrict__ Wqb, short* __restrict__ Wkb,
    short* __restrict__ Wvb, short* __restrict__ Wob)
{
  const int i = (blockIdx.x*256 + threadIdx.x)*8;
  const int seg = i >> 16;
  const int off = i & 65535;
  const float* src = seg==0?Wq: seg==1?Wk: seg==2?Wv:Wo;
  short* dst       = seg==0?Wqb: seg==1?Wkb: seg==2?Wvb:Wob;
  const float sc = (seg==0) ? QSCALE : 1.0f;
  float4 a = *(const float4*)(src + off);
  float4 b = *(const float4*)(src + off + 4);
  s16x8 o;
  o[0]=f2bf(a.x*sc); o[1]=f2bf(a.y*sc); o[2]=f2bf(a.z*sc); o[3]=f2bf(a.w*sc);
  o[4]=f2bf(b.x*sc); o[5]=f2bf(b.y*sc); o[6]=f2bf(b.z*sc); o[7]=f2bf(b.w*sc);
  const int row = off >> 8, col = off & 255;
  *(s16x8*)(dst + WFRAG(row>>4, col>>5, (col>>3)&3, row&15)) = o;
}

// ---------------------------------------------------------------------------
// QKV projection (r15 shape): bf16 packed W, n-split=2 (8 n-frags/wave),
// block = 2 waves x 16 rows, grid (MTOT/32, 2, 3).
// mode 0/1 (Q,K): SWAPPED mfma(W,X) -> s16x4 stores.
// mode 2 (V): original order, TILED [b,h][kv_tile][d=32][kv_in=32] layout.
// ---------------------------------------------------------------------------
__global__ __launch_bounds__(128) void qkv_proj(
    const float* __restrict__ Xq, const float* __restrict__ Xk, const float* __restrict__ Xv,
    const short* __restrict__ Wqb, const short* __restrict__ Wkb, const short* __restrict__ Wvb,
    const float* __restrict__ bq, const float* __restrict__ bk, const float* __restrict__ bv,
    short* __restrict__ Qh, short* __restrict__ Kh, short* __restrict__ Vt)
{
  const int mode = blockIdx.z;
  const float* X    = mode==0 ? Xq : (mode==1 ? Xk : Xv);
  const short* Wb   = mode==0 ? Wqb : (mode==1 ? Wkb : Wvb);
  const float* bias = mode==0 ? bq : (mode==1 ? bk : bv);
  short* dst        = mode==0 ? Qh : (mode==1 ? Kh : Vt);
  const float bscale = (mode==0) ? QSCALE : 1.0f;

  const int wid = threadIdx.x >> 6, lane = threadIdx.x & 63;
  const int lr = lane & 15, lg = lane >> 4;
  const int m0 = blockIdx.x*32 + wid*16;
  const int nf0 = blockIdx.y*8;

  f32x4 acc[8] = {};
  const int bb = m0 >> 11;

  if (mode < 2) {
    // ---- swapped: D[outcol][m], lane: m = m0+lr, cols = nf*16 + lg*4 + r
    #pragma unroll
    for (int kc = 0; kc < 8; ++kc) {
      const int k0 = kc*32 + lg*8;
      const float* ap = X + (size_t)(m0 + lr)*DM + k0;
      float4 a0 = *(const float4*)ap;
      float4 a1 = *(const float4*)(ap + 4);
      bf16x8 a;
      a[0]=(__bf16)a0.x; a[1]=(__bf16)a0.y; a[2]=(__bf16)a0.z; a[3]=(__bf16)a0.w;
      a[4]=(__bf16)a1.x; a[5]=(__bf16)a1.y; a[6]=(__bf16)a1.z; a[7]=(__bf16)a1.w;
      #pragma unroll
      for (int nfi=0; nfi<8; ++nfi) {
        bf16x8 b = *(const bf16x8*)(Wb + WFRAG(nf0+nfi, kc, lg, lr));
        acc[nfi] = __builtin_amdgcn_mfma_f32_16x16x32_bf16(b, a, acc[nfi], 0,0,0);
      }
    }
    const int m = m0 + lr;
    const int l = m & (SEQ-1);
    #pragma unroll
    for (int nfi=0; nfi<8; ++nfi) {
      const int colbase = (nf0+nfi)*16;
      const int h = colbase >> 5;
      const int dbase = (colbase & 31) + lg*4;
      float4 b4 = *(const float4*)(bias + colbase + lg*4);
      s16x4 pk;
      pk[0] = f2bf(acc[nfi][0] + b4.x*bscale);
      pk[1] = f2bf(acc[nfi][1] + b4.y*bscale);
      pk[2] = f2bf(acc[nfi][2] + b4.z*bscale);
      pk[3] = f2bf(acc[nfi][3] + b4.w*bscale);
      *(s16x4*)(dst + ((size_t)(bb*NHEADS + h)*SEQ + l)*DH + dbase) = pk;
    }
  } else {
    // ---- original: D[m][outcol], lane: col = nf*16+lr, rows = li0 + r
    #pragma unroll
    for (int kc = 0; kc < 8; ++kc) {
      const int k0 = kc*32 + lg*8;
      const float* ap = X + (size_t)(m0 + lr)*DM + k0;
      float4 a0 = *(const float4*)ap;
      float4 a1 = *(const float4*)(ap + 4);
      bf16x8 a;
      a[0]=(__bf16)a0.x; a[1]=(__bf16)a0.y; a[2]=(__bf16)a0.z; a[3]=(__bf16)a0.w;
      a[4]=(__bf16)a1.x; a[5]=(__bf16)a1.y; a[6]=(__bf16)a1.z; a[7]=(__bf16)a1.w;
      #pragma unroll
      for (int nfi=0; nfi<8; ++nfi) {
        bf16x8 b = *(const bf16x8*)(Wb + WFRAG(nf0+nfi, kc, lg, lr));
        acc[nfi] = __builtin_amdgcn_mfma_f32_16x16x32_bf16(a, b, acc[nfi], 0,0,0);
      }
    }
    const int li0 = (m0 & (SEQ-1)) + lg*4;
    #pragma unroll
    for (int nfi=0; nfi<8; ++nfi) {
      const int col = (nf0+nfi)*16 + lr;
      const float bv_ = bias[col];
      const int h = col >> 5, d = col & 31;
      s16x4 pk;
      #pragma unroll
      for (int r=0;r<4;r++) pk[r] = f2bf(acc[nfi][r] + bv_);
      *(s16x4*)(dst + (((size_t)(bb*NHEADS + h)*(SEQ/32) + (li0>>5))*DH + d)*32 + (li0&31)) = pk;
    }
  }
}

// ---------------------------------------------------------------------------
// Flash attention: 32x32x16 MFMA, swapped-QK, no max tracking, no kv-split
// (4 adjacent q-tiles share kv via L1), no LDS, no barriers, dual
// accumulator chains, distance-1 prefetch. ctx FRAGMENT-PACKED (r25 win).
// NEW (r26): setprio REMOVED from ATTN_TILE — setprio is a side-effecting
// intrinsic the scheduler can't reorder across, so the r21 dual chains were
// order-pinned and could never interleave; removing the fences lets chain
// A's softmax overlap chain B's MFMAs. (setprio itself measured null, r18.)
// ---------------------------------------------------------------------------
#if __has_builtin(__builtin_amdgcn_permlane32_swap)
typedef unsigned int u32x2v __attribute__((ext_vector_type(2)));
#define PSWAP(a_, b_) do { u32x2v r_ = __builtin_amdgcn_permlane32_swap((a_), (b_), false, false); (a_) = r_[0]; (b_) = r_[1]; } while(0)
#else
#define PSWAP(a_, b_) asm("s_nop 1\n\tv_permlane32_swap_b32 %0, %1" : "+v"(a_), "+v"(b_))
#endif

#define LOADKV(K0_,K1_,V0_,V1_, kvb_) do { \
  const short* kp_ = Kb + (size_t)((kvb_) + l31)*DH + hi8; \
  K0_ = *(const bf16x8*)kp_; K1_ = *(const bf16x8*)(kp_ + 16); \
  const short* vp_ = Vb + ((size_t)(((kvb_) >> 5)*32) + l31)*32 + hi8; \
  V0_ = *(const bf16x8*)vp_; V1_ = *(const bf16x8*)(vp_ + 16); \
} while(0)

#define ATTN_TILE(O_, l_, K0_, K1_, V0_, V1_) do { \
  f32x16 S_ = __builtin_amdgcn_mfma_f32_32x32x16_bf16(K0_, Q0, zf16, 0,0,0); \
  S_ = __builtin_amdgcn_mfma_f32_32x32x16_bf16(K1_, Q1, S_, 0,0,0); \
  float p_[16]; \
  _Pragma("unroll") for (int r_=0;r_<16;r_++) p_[r_] = __builtin_amdgcn_exp2f(S_[r_]); \
  l_ += (((p_[0]+p_[1])+(p_[2]+p_[3]))+((p_[4]+p_[5])+(p_[6]+p_[7]))) \
      + (((p_[8]+p_[9])+(p_[10]+p_[11]))+((p_[12]+p_[13])+(p_[14]+p_[15]))); \
  uint32_t pa_, pb_, pc_, pd_; \
  asm("v_cvt_pk_bf16_f32 %0, %1, %2" : "=v"(pa_) : "v"(p_[0]), "v"(p_[1])); \
  asm("v_cvt_pk_bf16_f32 %0, %1, %2" : "=v"(pb_) : "v"(p_[2]), "v"(p_[3])); \
  asm("v_cvt_pk_bf16_f32 %0, %1, %2" : "=v"(pc_) : "v"(p_[4]), "v"(p_[5])); \
  asm("v_cvt_pk_bf16_f32 %0, %1, %2" : "=v"(pd_) : "v"(p_[6]), "v"(p_[7])); \
  PSWAP(pa_, pc_); PSWAP(pb_, pd_); \
  { u32x4 w_ = {pa_, pb_, pc_, pd_}; \
    O_ = __builtin_amdgcn_mfma_f32_32x32x16_bf16(V0_, __builtin_bit_cast(bf16x8, w_), O_, 0,0,0); } \
  asm("v_cvt_pk_bf16_f32 %0, %1, %2" : "=v"(pa_) : "v"(p_[8]),  "v"(p_[9])); \
  asm("v_cvt_pk_bf16_f32 %0, %1, %2" : "=v"(pb_) : "v"(p_[10]), "v"(p_[11])); \
  asm("v_cvt_pk_bf16_f32 %0, %1, %2" : "=v"(pc_) : "v"(p_[12]), "v"(p_[13])); \
  asm("v_cvt_pk_bf16_f32 %0, %1, %2" : "=v"(pd_) : "v"(p_[14]), "v"(p_[15])); \
  PSWAP(pa_, pc_); PSWAP(pb_, pd_); \
  { u32x4 w_ = {pa_, pb_, pc_, pd_}; \
    O_ = __builtin_amdgcn_mfma_f32_32x32x16_bf16(V1_, __builtin_bit_cast(bf16x8, w_), O_, 0,0,0); } \
} while(0)

__global__ __launch_bounds__(256, 2) void attn(
    const short* __restrict__ Qh, const short* __restrict__ Kh,
    const short* __restrict__ Vt, short* __restrict__ ctx)
{
  const int wid = threadIdx.x >> 6, lane = threadIdx.x & 63;
  const int l31 = lane & 31, hi8 = (lane >> 5)*8;
  const int bh = blockIdx.x;              // XCD = bh & 7 (32 % 8 == 0)
  const int q0 = blockIdx.y*128 + wid*32; // 4 q-tiles per block, same kv seq

  const short* Kb = Kh + (size_t)bh*SEQ*DH;
  const short* Vb = Vt + (size_t)bh*SEQ*DH;   // tiled layout

  const short* qp = Qh + ((size_t)bh*SEQ + q0 + l31)*DH + hi8;
  const bf16x8 Q0 = *(const bf16x8*)(qp);
  const bf16x8 Q1 = *(const bf16x8*)(qp + 16);

  f32x16 Oa = {}, Ob = {};
  float lrunA = 0.f, lrunB = 0.f;
  const f32x16 zf16 = {};

  bf16x8 Ka0,Ka1,Va0,Va1, Kc0,Kc1,Vc0,Vc1;
  LOADKV(Ka0,Ka1,Va0,Va1, 0);

  #pragma unroll 2
  for (int t = 0; t < 64; t += 2) {      // full kv sweep: 64 tiles of 32
    LOADKV(Kc0,Kc1,Vc0,Vc1, (t+1)*32);
    ATTN_TILE(Oa, lrunA, Ka0,Ka1,Va0,Va1);
    LOADKV(Ka0,Ka1,Va0,Va1, ((t+2)&63)*32);
    ATTN_TILE(Ob, lrunB, Kc0,Kc1,Vc0,Vc1);
  }

  float lrun = lrunA + lrunB;
  lrun += __shfl_xor(lrun, 32);          // both kv-row halves of this wave

  const float inv = 1.0f / lrun;
  // packed ctx (verified r22/r25): elem (m, col=hh*32+dd) at
  // WFRAG(m>>4, hh, dd>>3, m&15) + (dd&7); lane: q=l31, dd = rg*8 + j0 + r
  const int bb = bh >> 3, hh = bh & 7;
  const int mt8 = (((bb*SEQ) + q0 + l31) >> 4)*8 + hh;
  const int lrr = l31 & 15;
  const int j0  = hi8 >> 1;
  short* cp = ctx + (size_t)mt8*512;     // [4 lg][16 lr][8]
  #pragma unroll
  for (int rg=0; rg<4; ++rg) {
    s16x4 o;
    #pragma unroll
    for (int r=0;r<4;r++) o[r] = f2bf((Oa[rg*4+r] + Ob[rg*4+r])*inv);
    *(s16x4*)(cp + (rg*16 + lrr)*8 + j0) = o;
  }
}

// ---------------------------------------------------------------------------
// out = ctx @ Wo^T + bo; x = out + query; LayerNorm(x).
// SWAPPED mfma(Wo, ctx); BOTH operands fragment-packed (contiguous 1KB wave
// loads). float4 resid/bias/gamma/beta loads, float4 out stores.
// LN: in-lane sum + 2 shfl_xor + tiny LDS cross-wave exchange.
// ---------------------------------------------------------------------------
__global__ __launch_bounds__(256) void out_ln(
    const short* __restrict__ ctx, const short* __restrict__ Wob,
    const float* __restrict__ bo, const float* __restrict__ resid,
    const float* __restrict__ ln_g, const float* __restrict__ ln_b,
    float* __restrict__ out)
{
  __shared__ float2 red[4][16];
  const int wid = threadIdx.x >> 6, lane = threadIdx.x & 63;
  const int lr = lane & 15, lg = lane >> 4;
  const int m0 = blockIdx.x*16;
  const int c0 = wid*64;
  const int m  = m0 + lr;
  const int cb = c0 + lg*4;              // this lane's col base (per nf: +16)
  const int mt = m0 >> 4;

  // hoisted epilogue operands (vector loads, issued before the GEMM loop)
  float4 rs_[4], bo_[4], g_[4], b_[4];
  #pragma unroll
  for (int nf=0; nf<4; ++nf) {
    const int col = cb + nf*16;
    bo_[nf] = *(const float4*)(bo + col);
    g_[nf]  = *(const float4*)(ln_g + col);
    b_[nf]  = *(const float4*)(ln_b + col);
    rs_[nf] = *(const float4*)(resid + (size_t)m*DM + col);
  }
  __builtin_amdgcn_sched_barrier(0);

  f32x4 acc[4] = {};
  #pragma unroll
  for (int kc=0; kc<8; ++kc) {
    bf16x8 a = *(const bf16x8*)(ctx + WFRAG(mt, kc, lg, lr));
    #pragma unroll
    for (int nf=0; nf<4; ++nf) {
      bf16x8 b = *(const bf16x8*)(Wob + WFRAG(wid*4+nf, kc, lg, lr));
      acc[nf] = __builtin_amdgcn_mfma_f32_16x16x32_bf16(b, a, acc[nf], 0,0,0);
    }
  }

  // x = acc + bo + resid ; partial LN stats for row m over this wave's 64 cols
  float xv[4][4];
  float s = 0.f, s2 = 0.f;
  #pragma unroll
  for (int nf=0; nf<4; ++nf) {
    const float* bp = (const float*)&bo_[nf];
    const float* rp = (const float*)&rs_[nf];
    #pragma unroll
    for (int r=0;r<4;r++) {
      float v = acc[nf][r] + bp[r] + rp[r];
      xv[nf][r] = v; s += v; s2 += v*v;
    }
  }
  s  += __shfl_xor(s, 16);  s  += __shfl_xor(s, 32);
  s2 += __shfl_xor(s2, 16); s2 += __shfl_xor(s2, 32);
  if (lane < 16) red[wid][lr] = make_float2(s, s2);
  __syncthreads();
  s = 0.f; s2 = 0.f;
  #pragma unroll
  for (int w=0;w<4;w++){ float2 t = red[w][lr]; s += t.x; s2 += t.y; }
  const float mean = s * (1.0f/DM);
  const float var  = s2 * (1.0f/DM) - mean*mean;
  const float rstd = rsqrtf(var + 1e-5f);
  #pragma unroll
  for (int nf=0; nf<4; ++nf) {
    const float* gp = (const float*)&g_[nf];
    const float* bp = (const float*)&b_[nf];
    float4 o;
    o.x = (xv[nf][0]-mean)*rstd*gp[0] + bp[0];
    o.y = (xv[nf][1]-mean)*rstd*gp[1] + bp[1];
    o.z = (xv[nf][2]-mean)*rstd*gp[2] + bp[2];
    o.w = (xv[nf][3]-mean)*rstd*gp[3] + bp[3];
    *(float4*)(out + (size_t)m*DM + cb + nf*16) = o;
  }
}

extern "C" void kernel_launch(void* const* d_in, const int* in_sizes, int n_in,
                              void* d_out, int out_size, void* d_ws, size_t ws_size,
                              hipStream_t stream) {
  const float* query = (const float*)d_in[0];
  const float* key   = (const float*)d_in[1];
  const float* value = (const float*)d_in[2];
  const float* Wq    = (const float*)d_in[3];
  const float* bq    = (const float*)d_in[4];
  const float* Wk    = (const float*)d_in[5];
  const float* bk    = (const float*)d_in[6];
  const float* Wv    = (const float*)d_in[7];
  const float* bv    = (const float*)d_in[8];
  const float* Wo    = (const float*)d_in[9];
  const float* bo    = (const float*)d_in[10];
  const float* ln_g  = (const float*)d_in[11];
  const float* ln_b  = (const float*)d_in[12];
  float* out = (float*)d_out;

  const size_t HSZ = (size_t)NB*NHEADS*SEQ*DH;   // 2,097,152
  short* Qh  = (short*)d_ws;
  short* Kh  = Qh + HSZ;
  short* Vt  = Kh + HSZ;
  short* ctx = Vt + HSZ;                 // packed layout, same size
  short* Wqb = ctx + (size_t)MTOT*DM;
  short* Wkb = Wqb + DM*DM;
  short* Wvb = Wkb + DM*DM;
  short* Wob = Wvb + DM*DM;   // total ws: ~17 MB

  prep<<<dim3(128), 256, 0, stream>>>(Wq, Wk, Wv, Wo, Wqb, Wkb, Wvb, Wob);
  qkv_proj<<<dim3(MTOT/32, 2, 3), 128, 0, stream>>>(
      query, key, value, Wqb, Wkb, Wvb, bq, bk, bv, Qh, Kh, Vt);
  attn<<<dim3(NB*NHEADS, SEQ/128), 256, 0, stream>>>(Qh, Kh, Vt, ctx);
  out_ln<<<dim3(MTOT/16), 256, 0, stream>>>(ctx, Wob, bo, query, ln_g, ln_b, out);
}